// Round 7
// baseline (31.014 us; speedup 1.0000x reference)
//
#include <hip/hip_runtime.h>

constexpr int C_ = 1000;
constexpr int A_ = 512;
constexpr int N_ = 65536;
constexpr int CA_ = C_ * A_;
constexpr float ONE_MINUS_M = 0.2f;   // 1 - MOMENTUM

constexpr int TPB    = 512;           // 4 row-groups x 128 col-threads
constexpr int NCHUNK = 8;
constexpr int RPC    = N_ / NCHUNK;   // 8192 rows per chunk
constexpr int I4PT   = RPC / 4 / TPB; // 4 int4 label loads per thread per chunk
constexpr int CAP    = 512;           // per-chunk per-class row bound (mean ~8)

// One block per class. Software-pipelined: while gathering chunk k's rows
// (HBM-heavy), the labels of chunk k+1 are already in flight from L2.
// RACE FIX (R7): barrier between the cnt_b read and the lcnt[b] reset —
// without it, tid0's wave can zero the counter before slower waves read it
// (observed as nondeterministic absmax 0.38 in R6).
__global__ __launch_bounds__(TPB, 8) void fused_kernel(
    const float* __restrict__ feat, const int* __restrict__ labels,
    const float* __restrict__ cov, const float* __restrict__ mean,
    const float* __restrict__ amount, float* __restrict__ out)
{
    __shared__ int   lrows[2][CAP];
    __shared__ int   lcnt[2];
    __shared__ float lred[3 * 128 * 9];   // groups 1..3 partials, stride 9

    const int c   = blockIdx.x;
    const int tid = threadIdx.x;
    if (tid < 2) lcnt[tid] = 0;
    __syncthreads();

    const int4* lab4 = reinterpret_cast<const int4*>(labels);

    const int g  = tid >> 7;      // row group 0..3
    const int ct = tid & 127;     // col thread
    const int cb = ct * 4;        // column base (float4)

    float4 s = {0.f, 0.f, 0.f, 0.f};
    float4 q = {0.f, 0.f, 0.f, 0.f};
    int cnt_total = 0;

    // ---- prologue: filter chunk 0 into list 0 ----
    int4 L[I4PT];
    #pragma unroll
    for (int u = 0; u < I4PT; ++u) L[u] = lab4[u * TPB + tid];
    #pragma unroll
    for (int u = 0; u < I4PT; ++u) {
        const int r0 = (u * TPB + tid) * 4;
        int ix;
        if (L[u].x == c) { ix = atomicAdd(&lcnt[0], 1); if (ix < CAP) lrows[0][ix] = r0;     }
        if (L[u].y == c) { ix = atomicAdd(&lcnt[0], 1); if (ix < CAP) lrows[0][ix] = r0 + 1; }
        if (L[u].z == c) { ix = atomicAdd(&lcnt[0], 1); if (ix < CAP) lrows[0][ix] = r0 + 2; }
        if (L[u].w == c) { ix = atomicAdd(&lcnt[0], 1); if (ix < CAP) lrows[0][ix] = r0 + 3; }
    }
    __syncthreads();

    for (int k = 0; k < NCHUNK; ++k) {
        const int b     = k & 1;
        const int cnt_b = min(lcnt[b], CAP);   // list b is complete (sync'd)
        cnt_total += cnt_b;
        __syncthreads();                       // ALL reads of lcnt[b] done (race fix)
        if (tid == 0) lcnt[b] = 0;             // safe: visible by end-of-loop barrier

        // (a) issue next chunk's label loads — in flight during the gather
        if (k < NCHUNK - 1) {
            #pragma unroll
            for (int u = 0; u < I4PT; ++u)
                L[u] = lab4[(k + 1) * (RPC / 4) + u * TPB + tid];
        }

        // (b) gather this chunk's rows (group g owns rows g, g+4, ...)
        int r = g;
        for (; r + 4 < cnt_b; r += 8) {        // 2 rows in flight
            const int r0 = lrows[b][r];
            const int r1 = lrows[b][r + 4];
            const float4 a0 = *reinterpret_cast<const float4*>(feat + (size_t)r0 * A_ + cb);
            const float4 a1 = *reinterpret_cast<const float4*>(feat + (size_t)r1 * A_ + cb);
            s.x += a0.x; s.y += a0.y; s.z += a0.z; s.w += a0.w;
            q.x = fmaf(a0.x, a0.x, q.x); q.y = fmaf(a0.y, a0.y, q.y);
            q.z = fmaf(a0.z, a0.z, q.z); q.w = fmaf(a0.w, a0.w, q.w);
            s.x += a1.x; s.y += a1.y; s.z += a1.z; s.w += a1.w;
            q.x = fmaf(a1.x, a1.x, q.x); q.y = fmaf(a1.y, a1.y, q.y);
            q.z = fmaf(a1.z, a1.z, q.z); q.w = fmaf(a1.w, a1.w, q.w);
        }
        for (; r < cnt_b; r += 4) {
            const int r0 = lrows[b][r];
            const float4 a0 = *reinterpret_cast<const float4*>(feat + (size_t)r0 * A_ + cb);
            s.x += a0.x; s.y += a0.y; s.z += a0.z; s.w += a0.w;
            q.x = fmaf(a0.x, a0.x, q.x); q.y = fmaf(a0.y, a0.y, q.y);
            q.z = fmaf(a0.z, a0.z, q.z); q.w = fmaf(a0.w, a0.w, q.w);
        }

        // (c) append next chunk's matches to the other list
        if (k < NCHUNK - 1) {
            const int nb = b ^ 1;
            #pragma unroll
            for (int u = 0; u < I4PT; ++u) {
                const int r0 = ((k + 1) * (RPC / 4) + u * TPB + tid) * 4;
                int ix;
                if (L[u].x == c) { ix = atomicAdd(&lcnt[nb], 1); if (ix < CAP) lrows[nb][ix] = r0;     }
                if (L[u].y == c) { ix = atomicAdd(&lcnt[nb], 1); if (ix < CAP) lrows[nb][ix] = r0 + 1; }
                if (L[u].z == c) { ix = atomicAdd(&lcnt[nb], 1); if (ix < CAP) lrows[nb][ix] = r0 + 2; }
                if (L[u].w == c) { ix = atomicAdd(&lcnt[nb], 1); if (ix < CAP) lrows[nb][ix] = r0 + 3; }
            }
        }
        __syncthreads();
    }

    // ---- cross-group combine + fused finalize ----
    if (g > 0) {
        float* p = &lred[((g - 1) * 128 + ct) * 9];
        p[0] = s.x; p[1] = s.y; p[2] = s.z; p[3] = s.w;
        p[4] = q.x; p[5] = q.y; p[6] = q.z; p[7] = q.w;
    }
    __syncthreads();
    if (g == 0) {
        #pragma unroll
        for (int gg = 0; gg < 3; ++gg) {
            const float* p = &lred[(gg * 128 + ct) * 9];
            s.x += p[0]; s.y += p[1]; s.z += p[2]; s.w += p[3];
            q.x += p[4]; q.y += p[5]; q.z += p[6]; q.w += p[7];
        }
        const int   cntc = cnt_total;
        const float cntf = (float)cntc;
        const float safe = (cntc == 0) ? 1.f : cntf;
        const float inv  = 1.f / safe;
        float4 ave, var;
        ave.x = s.x * inv; ave.y = s.y * inv; ave.z = s.z * inv; ave.w = s.w * inv;
        var.x = fmaxf(q.x * inv - ave.x * ave.x, 0.f);
        var.y = fmaxf(q.y * inv - ave.y * ave.y, 0.f);
        var.z = fmaxf(q.z * inv - ave.z * ave.z, 0.f);
        var.w = fmaxf(q.w * inv - ave.w * ave.w, 0.f);

        const float amt   = amount[c];
        const float den   = cntf + amt;
        const float w_raw = (den > 0.f) ? (cntf / den) : 0.f;
        const float w     = (w_raw > 0.f) ? fmaxf(w_raw, ONE_MINUS_M) : 0.f;
        const float omw   = 1.f - w;

        const int idx = c * A_ + cb;
        const float4 m  = *reinterpret_cast<const float4*>(mean + idx);
        const float4 cv = *reinterpret_cast<const float4*>(cov + idx);
        const float dx = m.x - ave.x, dy = m.y - ave.y,
                    dz = m.z - ave.z, dw = m.w - ave.w;
        float4 oc, om;
        oc.x = cv.x * omw + var.x * w + w * omw * dx * dx;
        oc.y = cv.y * omw + var.y * w + w * omw * dy * dy;
        oc.z = cv.z * omw + var.z * w + w * omw * dz * dz;
        oc.w = cv.w * omw + var.w * w + w * omw * dw * dw;
        om.x = m.x * omw + ave.x * w;
        om.y = m.y * omw + ave.y * w;
        om.z = m.z * omw + ave.z * w;
        om.w = m.w * omw + ave.w * w;
        *reinterpret_cast<float4*>(out + idx)       = oc;
        *reinterpret_cast<float4*>(out + CA_ + idx) = om;
        if (ct == 0) out[2 * CA_ + c] = amt + cntf;
    }
}

extern "C" void kernel_launch(void* const* d_in, const int* in_sizes, int n_in,
                              void* d_out, int out_size, void* d_ws, size_t ws_size,
                              hipStream_t stream)
{
    const float* feat   = (const float*)d_in[0];
    const int*   labels = (const int*)  d_in[1];
    const float* cov    = (const float*)d_in[2];
    const float* mean   = (const float*)d_in[3];
    const float* amount = (const float*)d_in[4];
    float* out = (float*)d_out;

    fused_kernel<<<C_, TPB, 0, stream>>>(feat, labels, cov, mean, amount, out);
}

// Round 8
// 30.645 us; speedup vs baseline: 1.0120x; 1.0120x over previous
//
#include <hip/hip_runtime.h>

constexpr int C_ = 1000;
constexpr int A_ = 512;
constexpr int N_ = 65536;
constexpr int CA_ = C_ * A_;
constexpr float ONE_MINUS_M = 0.2f;   // 1 - MOMENTUM

constexpr int TPB    = 512;           // 4 row-groups x 128 col-threads
constexpr int NCHUNK = 8;
constexpr int RPC    = N_ / NCHUNK;   // 8192 rows per chunk
constexpr int I4PT   = RPC / 4 / TPB; // 4 int4 label loads per thread per chunk
constexpr int CAP    = 512;           // per-chunk per-class row bound (mean ~8)

// One block per class, software-pipelined filter-under-gather.
// R8: per-chunk DEDICATED counters (lcnt[k], never reset) — chunk k's filter
// appends to lcnt[k+1], gather reads lcnt[k]. Removes the reset race class
// entirely and needs only ONE barrier per chunk (R7 needed two).
__global__ __launch_bounds__(TPB, 8) void fused_kernel(
    const float* __restrict__ feat, const int* __restrict__ labels,
    const float* __restrict__ cov, const float* __restrict__ mean,
    const float* __restrict__ amount, float* __restrict__ out)
{
    __shared__ int   lrows[2][CAP];
    __shared__ int   lcnt[NCHUNK + 1];
    __shared__ float lred[3 * 128 * 9];   // groups 1..3 partials, stride 9

    const int c   = blockIdx.x;
    const int tid = threadIdx.x;
    if (tid <= NCHUNK) lcnt[tid] = 0;
    __syncthreads();

    const int4* lab4 = reinterpret_cast<const int4*>(labels);

    const int g  = tid >> 7;      // row group 0..3
    const int ct = tid & 127;     // col thread
    const int cb = ct * 4;        // column base (float4)

    float4 s = {0.f, 0.f, 0.f, 0.f};
    float4 q = {0.f, 0.f, 0.f, 0.f};
    int cnt_total = 0;

    // ---- prologue: filter chunk 0 into list 0 / counter 0 ----
    int4 L[I4PT];
    #pragma unroll
    for (int u = 0; u < I4PT; ++u) L[u] = lab4[u * TPB + tid];
    #pragma unroll
    for (int u = 0; u < I4PT; ++u) {
        const int r0 = (u * TPB + tid) * 4;
        int ix;
        if (L[u].x == c) { ix = atomicAdd(&lcnt[0], 1); if (ix < CAP) lrows[0][ix] = r0;     }
        if (L[u].y == c) { ix = atomicAdd(&lcnt[0], 1); if (ix < CAP) lrows[0][ix] = r0 + 1; }
        if (L[u].z == c) { ix = atomicAdd(&lcnt[0], 1); if (ix < CAP) lrows[0][ix] = r0 + 2; }
        if (L[u].w == c) { ix = atomicAdd(&lcnt[0], 1); if (ix < CAP) lrows[0][ix] = r0 + 3; }
    }
    __syncthreads();

    for (int k = 0; k < NCHUNK; ++k) {
        const int b     = k & 1;
        const int cnt_b = min(lcnt[k], CAP);   // complete: end barrier of k-1
        cnt_total += cnt_b;

        // (a) issue next chunk's label loads — in flight during the gather
        if (k < NCHUNK - 1) {
            #pragma unroll
            for (int u = 0; u < I4PT; ++u)
                L[u] = lab4[(k + 1) * (RPC / 4) + u * TPB + tid];
        }

        // (b) gather this chunk's rows (group g owns rows g, g+4, ...)
        int r = g;
        for (; r + 12 < cnt_b; r += 16) {      // 4 rows in flight
            int ri[4];
            #pragma unroll
            for (int u = 0; u < 4; ++u) ri[u] = lrows[b][r + 4 * u];
            float4 v[4];
            #pragma unroll
            for (int u = 0; u < 4; ++u)
                v[u] = *reinterpret_cast<const float4*>(feat + (size_t)ri[u] * A_ + cb);
            #pragma unroll
            for (int u = 0; u < 4; ++u) {
                s.x += v[u].x; s.y += v[u].y; s.z += v[u].z; s.w += v[u].w;
                q.x = fmaf(v[u].x, v[u].x, q.x); q.y = fmaf(v[u].y, v[u].y, q.y);
                q.z = fmaf(v[u].z, v[u].z, q.z); q.w = fmaf(v[u].w, v[u].w, q.w);
            }
        }
        for (; r + 4 < cnt_b; r += 8) {        // 2 rows in flight
            const int r0 = lrows[b][r];
            const int r1 = lrows[b][r + 4];
            const float4 a0 = *reinterpret_cast<const float4*>(feat + (size_t)r0 * A_ + cb);
            const float4 a1 = *reinterpret_cast<const float4*>(feat + (size_t)r1 * A_ + cb);
            s.x += a0.x; s.y += a0.y; s.z += a0.z; s.w += a0.w;
            q.x = fmaf(a0.x, a0.x, q.x); q.y = fmaf(a0.y, a0.y, q.y);
            q.z = fmaf(a0.z, a0.z, q.z); q.w = fmaf(a0.w, a0.w, q.w);
            s.x += a1.x; s.y += a1.y; s.z += a1.z; s.w += a1.w;
            q.x = fmaf(a1.x, a1.x, q.x); q.y = fmaf(a1.y, a1.y, q.y);
            q.z = fmaf(a1.z, a1.z, q.z); q.w = fmaf(a1.w, a1.w, q.w);
        }
        for (; r < cnt_b; r += 4) {            // tail
            const int r0 = lrows[b][r];
            const float4 a0 = *reinterpret_cast<const float4*>(feat + (size_t)r0 * A_ + cb);
            s.x += a0.x; s.y += a0.y; s.z += a0.z; s.w += a0.w;
            q.x = fmaf(a0.x, a0.x, q.x); q.y = fmaf(a0.y, a0.y, q.y);
            q.z = fmaf(a0.z, a0.z, q.z); q.w = fmaf(a0.w, a0.w, q.w);
        }

        // (c) append next chunk's matches to the other list / next counter
        if (k < NCHUNK - 1) {
            const int nb = b ^ 1;
            #pragma unroll
            for (int u = 0; u < I4PT; ++u) {
                const int r0 = ((k + 1) * (RPC / 4) + u * TPB + tid) * 4;
                int ix;
                if (L[u].x == c) { ix = atomicAdd(&lcnt[k + 1], 1); if (ix < CAP) lrows[nb][ix] = r0;     }
                if (L[u].y == c) { ix = atomicAdd(&lcnt[k + 1], 1); if (ix < CAP) lrows[nb][ix] = r0 + 1; }
                if (L[u].z == c) { ix = atomicAdd(&lcnt[k + 1], 1); if (ix < CAP) lrows[nb][ix] = r0 + 2; }
                if (L[u].w == c) { ix = atomicAdd(&lcnt[k + 1], 1); if (ix < CAP) lrows[nb][ix] = r0 + 3; }
            }
        }
        __syncthreads();   // appends complete; lrows[b] free for reuse at k+2
    }

    // ---- cross-group combine + fused finalize ----
    if (g > 0) {
        float* p = &lred[((g - 1) * 128 + ct) * 9];
        p[0] = s.x; p[1] = s.y; p[2] = s.z; p[3] = s.w;
        p[4] = q.x; p[5] = q.y; p[6] = q.z; p[7] = q.w;
    }
    __syncthreads();
    if (g == 0) {
        #pragma unroll
        for (int gg = 0; gg < 3; ++gg) {
            const float* p = &lred[(gg * 128 + ct) * 9];
            s.x += p[0]; s.y += p[1]; s.z += p[2]; s.w += p[3];
            q.x += p[4]; q.y += p[5]; q.z += p[6]; q.w += p[7];
        }
        const int   cntc = cnt_total;
        const float cntf = (float)cntc;
        const float safe = (cntc == 0) ? 1.f : cntf;
        const float inv  = 1.f / safe;
        float4 ave, var;
        ave.x = s.x * inv; ave.y = s.y * inv; ave.z = s.z * inv; ave.w = s.w * inv;
        var.x = fmaxf(q.x * inv - ave.x * ave.x, 0.f);
        var.y = fmaxf(q.y * inv - ave.y * ave.y, 0.f);
        var.z = fmaxf(q.z * inv - ave.z * ave.z, 0.f);
        var.w = fmaxf(q.w * inv - ave.w * ave.w, 0.f);

        const float amt   = amount[c];
        const float den   = cntf + amt;
        const float w_raw = (den > 0.f) ? (cntf / den) : 0.f;
        const float w     = (w_raw > 0.f) ? fmaxf(w_raw, ONE_MINUS_M) : 0.f;
        const float omw   = 1.f - w;

        const int idx = c * A_ + cb;
        const float4 m  = *reinterpret_cast<const float4*>(mean + idx);
        const float4 cv = *reinterpret_cast<const float4*>(cov + idx);
        const float dx = m.x - ave.x, dy = m.y - ave.y,
                    dz = m.z - ave.z, dw = m.w - ave.w;
        float4 oc, om;
        oc.x = cv.x * omw + var.x * w + w * omw * dx * dx;
        oc.y = cv.y * omw + var.y * w + w * omw * dy * dy;
        oc.z = cv.z * omw + var.z * w + w * omw * dz * dz;
        oc.w = cv.w * omw + var.w * w + w * omw * dw * dw;
        om.x = m.x * omw + ave.x * w;
        om.y = m.y * omw + ave.y * w;
        om.z = m.z * omw + ave.z * w;
        om.w = m.w * omw + ave.w * w;
        *reinterpret_cast<float4*>(out + idx)       = oc;
        *reinterpret_cast<float4*>(out + CA_ + idx) = om;
        if (ct == 0) out[2 * CA_ + c] = amt + cntf;
    }
}

extern "C" void kernel_launch(void* const* d_in, const int* in_sizes, int n_in,
                              void* d_out, int out_size, void* d_ws, size_t ws_size,
                              hipStream_t stream)
{
    const float* feat   = (const float*)d_in[0];
    const int*   labels = (const int*)  d_in[1];
    const float* cov    = (const float*)d_in[2];
    const float* mean   = (const float*)d_in[3];
    const float* amount = (const float*)d_in[4];
    float* out = (float*)d_out;

    fused_kernel<<<C_, TPB, 0, stream>>>(feat, labels, cov, mean, amount, out);
}

// Round 9
// 29.250 us; speedup vs baseline: 1.0603x; 1.0477x over previous
//
#include <hip/hip_runtime.h>

constexpr int C_ = 1000;
constexpr int A_ = 512;
constexpr int N_ = 65536;
constexpr int CA_ = C_ * A_;
constexpr float ONE_MINUS_M = 0.2f;   // 1 - MOMENTUM

constexpr int TPB   = 512;            // 8 waves
constexpr int NW    = TPB / 64;       // 8 waves per block
constexpr int LPW   = N_ / NW;        // 8192 labels per wave
constexpr int ITERS = LPW / 4 / 64;   // 32 int4-iters per lane

// One block per class; each wave autonomously scans its 1/8 of the labels
// (int4 + 64-bit ballot) and gathers matching rows itself: lane l owns
// cols 8l..8l+7, so one row = one coalesced 2KB wave read. No LDS lists,
// no atomics, no mid-kernel barriers — waves drift freely, latency is
// hidden by TLP (32 waves/CU). Single final barrier for the 8-way combine.
__global__ __launch_bounds__(TPB, 8) void fused_kernel(
    const float* __restrict__ feat, const int* __restrict__ labels,
    const float* __restrict__ cov, const float* __restrict__ mean,
    const float* __restrict__ amount, float* __restrict__ out)
{
    __shared__ float lds_s[NW][A_];   // 16 KB
    __shared__ float lds_q[NW][A_];   // 16 KB
    __shared__ int   lds_cnt[NW];

    const int c  = blockIdx.x;
    const int wv = threadIdx.x >> 6;
    const int ln = threadIdx.x & 63;

    const int4* lab4  = reinterpret_cast<const int4*>(labels);
    const int   wbase = wv * (LPW / 4);    // int4 index base of this wave
    const int   colb  = ln * 8;            // this lane's 8 columns

    float4 s0 = {0,0,0,0}, s1 = {0,0,0,0};
    float4 q0 = {0,0,0,0}, q1 = {0,0,0,0};
    int cnt_w = 0;

    int4 L = lab4[wbase + ln];             // prefetched
    for (int it = 0; it < ITERS; ++it) {
        int4 Ln = {0,0,0,0};
        if (it + 1 < ITERS) Ln = lab4[wbase + (it + 1) * 64 + ln];  // in flight during mask work

        unsigned long long m[4];
        m[0] = __ballot(L.x == c);
        m[1] = __ballot(L.y == c);
        m[2] = __ballot(L.z == c);
        m[3] = __ballot(L.w == c);
        const int rbase = (wbase + it * 64) * 4;   // row of (bit b, comp k) = rbase + 4b + k

        #pragma unroll
        for (int comp = 0; comp < 4; ++comp) {
            unsigned long long mm = m[comp];
            cnt_w += (int)__popcll(mm);
            while (mm) {                            // wave-uniform loop: no divergence
                const int b = (int)__builtin_ctzll(mm);
                mm &= mm - 1;
                const int row = rbase + 4 * b + comp;
                const float* rp = feat + (size_t)row * A_ + colb;
                const float4 v0 = *reinterpret_cast<const float4*>(rp);
                const float4 v1 = *reinterpret_cast<const float4*>(rp + 4);
                s0.x += v0.x; s0.y += v0.y; s0.z += v0.z; s0.w += v0.w;
                s1.x += v1.x; s1.y += v1.y; s1.z += v1.z; s1.w += v1.w;
                q0.x = fmaf(v0.x, v0.x, q0.x); q0.y = fmaf(v0.y, v0.y, q0.y);
                q0.z = fmaf(v0.z, v0.z, q0.z); q0.w = fmaf(v0.w, v0.w, q0.w);
                q1.x = fmaf(v1.x, v1.x, q1.x); q1.y = fmaf(v1.y, v1.y, q1.y);
                q1.z = fmaf(v1.z, v1.z, q1.z); q1.w = fmaf(v1.w, v1.w, q1.w);
            }
        }
        L = Ln;
    }

    // ---- single combine: 8 waves x 512 cols ----
    if (ln == 0) lds_cnt[wv] = cnt_w;      // wave-uniform value
    *reinterpret_cast<float4*>(&lds_s[wv][colb])     = s0;
    *reinterpret_cast<float4*>(&lds_s[wv][colb + 4]) = s1;
    *reinterpret_cast<float4*>(&lds_q[wv][colb])     = q0;
    *reinterpret_cast<float4*>(&lds_q[wv][colb + 4]) = q1;
    __syncthreads();

    const int col = threadIdx.x;           // 512 threads -> 512 cols
    float s = 0.f, q = 0.f;
    #pragma unroll
    for (int w = 0; w < NW; ++w) { s += lds_s[w][col]; q += lds_q[w][col]; }
    int cntc = 0;
    #pragma unroll
    for (int w = 0; w < NW; ++w) cntc += lds_cnt[w];

    const float cntf = (float)cntc;
    const float safe = (cntc == 0) ? 1.f : cntf;
    const float inv  = 1.f / safe;
    const float ave  = s * inv;
    const float var  = fmaxf(q * inv - ave * ave, 0.f);

    const float amt   = amount[c];
    const float den   = cntf + amt;
    const float w_raw = (den > 0.f) ? (cntf / den) : 0.f;
    const float w     = (w_raw > 0.f) ? fmaxf(w_raw, ONE_MINUS_M) : 0.f;
    const float omw   = 1.f - w;

    const int idx = c * A_ + col;
    const float m  = mean[idx];
    const float cv = cov[idx];
    const float d  = m - ave;
    out[idx]       = cv * omw + var * w + w * omw * d * d;   // new_cov
    out[CA_ + idx] = m * omw + ave * w;                      // new_mean
    if (col == 0) out[2 * CA_ + c] = amt + cntf;
}

extern "C" void kernel_launch(void* const* d_in, const int* in_sizes, int n_in,
                              void* d_out, int out_size, void* d_ws, size_t ws_size,
                              hipStream_t stream)
{
    const float* feat   = (const float*)d_in[0];
    const int*   labels = (const int*)  d_in[1];
    const float* cov    = (const float*)d_in[2];
    const float* mean   = (const float*)d_in[3];
    const float* amount = (const float*)d_in[4];
    float* out = (float*)d_out;

    fused_kernel<<<C_, TPB, 0, stream>>>(feat, labels, cov, mean, amount, out);
}